// Round 1
// baseline (1511.210 us; speedup 1.0000x reference)
//
#include <hip/hip_runtime.h>

// ---------------------------------------------------------------------------
// Projection (fp32). 4 rows per block, 128 threads = one output column each.
// CHUNKED=0: Y[((bb*8+h)*L + l)*16 + dd]                      (row layout, V)
// CHUNKED=1: Y[(((bb*8+h)*4 + dd/4)*L + l)*4 + dd%4]   (chunk-major, Q and K)
// Chunk-major makes the attention score pass read 16B/lane CONTIGUOUS.
// ---------------------------------------------------------------------------
template<int CHUNKED>
__global__ __launch_bounds__(128) void proj_kernel(
    const float* __restrict__ X, const float* __restrict__ W,
    const float* __restrict__ bias, float* __restrict__ Y, int L)
{
  __shared__ float xs[4][128];
  int rb = blockIdx.x * 4;
  int c  = threadIdx.x;
#pragma unroll
  for (int i = 0; i < 4; ++i)
    xs[i][c] = X[(size_t)(rb + i) * 128 + c];
  __syncthreads();
  float b = bias[c];
  float a0 = b, a1 = b, a2 = b, a3 = b;
#pragma unroll 8
  for (int d = 0; d < 128; ++d) {
    float w = W[d * 128 + c];
    a0 = fmaf(xs[0][d], w, a0);
    a1 = fmaf(xs[1][d], w, a1);
    a2 = fmaf(xs[2][d], w, a2);
    a3 = fmaf(xs[3][d], w, a3);
  }
  int h = c >> 4, dd = c & 15;
  float av[4] = { a0, a1, a2, a3 };
#pragma unroll
  for (int i = 0; i < 4; ++i) {
    int row = rb + i;
    int bb = row / L;
    int l  = row - bb * L;
    if (CHUNKED)
      Y[(((size_t)(bb * 8 + h) * 4 + (dd >> 2)) * L + l) * 4 + (dd & 3)] = av[i];
    else
      Y[((size_t)(bb * 8 + h) * L + l) * 16 + dd] = av[i];
  }
}

// Guarded hybrid root step for f(u-shifted) = S2 - 1 over current support:
// exact segment root when discriminant real, else Newton.
static __device__ __forceinline__ float hstep(float f, float s1, float cnt)
{
  float arg = fmaf(-cnt, f, s1 * s1);
  return (arg > 0.f) ? f / (s1 + sqrtf(arg)) : f / (2.f * s1);
}

// ---------------------------------------------------------------------------
// Attention pass (fp32). One wave per 2 rows. Scores in registers
// (k = lane + 64*j). RowM/ColM are CHUNK-MAJOR ([bh][4][L][4f]) so the dense
// score loads are 16B/lane contiguous (1KB coalesced per instruction).
// ValM stays row-major (sparse gathers hit one 64B line per survivor).
// entmax15 tau: monotone-from-left hybrid solver, tau0 = max-1. Once support
// <= CAP, survivors compacted (value+index) into per-wave LDS; remaining
// iterations and P@V touch only survivors. A is written DENSELY from the
// live score registers after convergence (coalesced; no zero-fill+scatter).
// ---------------------------------------------------------------------------
template<int LROW, int LCOL>
__global__ __launch_bounds__(256) void attn_kernel(
    const float* __restrict__ RowM, const float* __restrict__ ColM,
    const float* __restrict__ ValM, float* __restrict__ Aout,
    float* __restrict__ OutWs)
{
  constexpr int J   = LCOL / 64;
  constexpr int CAP = 512;
  __shared__ float          sval[4][2][CAP];
  __shared__ unsigned short sidx[4][2][CAP];

  int ws   = threadIdx.x >> 6;                      // wave slot in block
  int pid  = blockIdx.x * 4 + ws;                   // row-pair id
  int lane = threadIdx.x & 63;
  int bh   = pid / (LROW / 2);
  int pr   = pid - bh * (LROW / 2);
  int row0 = pr * 2;
  int bb   = bh >> 3, h = bh & 7;

  float qf0[16], qf1[16];
  { const float* qb = RowM + (size_t)bh * LROW * 16;   // chunk-major block
#pragma unroll
    for (int d = 0; d < 16; ++d) {
      qf0[d] = qb[((size_t)(d >> 2) * LROW + row0)     * 4 + (d & 3)] * 0.125f;
      qf1[d] = qb[((size_t)(d >> 2) * LROW + row0 + 1) * 4 + (d & 3)] * 0.125f;
    } }

  // -------- scores (raw; max folded into tau0) --------
  float x0[J], x1[J];
  const float4* Cb = (const float4*)(ColM + (size_t)bh * LCOL * 16);
#pragma unroll
  for (int j = 0; j < J; ++j) {
    int kk = lane + 64 * j;
    float4 k0 = Cb[0 * LCOL + kk];      // each: 16B/lane contiguous -> 1KB
    float4 k1 = Cb[1 * LCOL + kk];
    float4 k2 = Cb[2 * LCOL + kk];
    float4 k3 = Cb[3 * LCOL + kk];
    float kf[16] = { k0.x, k0.y, k0.z, k0.w, k1.x, k1.y, k1.z, k1.w,
                     k2.x, k2.y, k2.z, k2.w, k3.x, k3.y, k3.z, k3.w };
    float s0 = 0.f, s1 = 0.f;
#pragma unroll
    for (int d = 0; d < 16; ++d) {
      s0 = fmaf(qf0[d], kf[d], s0);
      s1 = fmaf(qf1[d], kf[d], s1);
    }
    x0[j] = s0; x1[j] = s1;
  }

  float m0 = -1e30f, m1 = -1e30f;
#pragma unroll
  for (int j = 0; j < J; ++j) { m0 = fmaxf(m0, x0[j]); m1 = fmaxf(m1, x1[j]); }
#pragma unroll
  for (int off = 32; off >= 1; off >>= 1) {
    m0 = fmaxf(m0, __shfl_xor(m0, off));
    m1 = fmaxf(m1, __shfl_xor(m1, off));
  }

  float tau0 = m0 - 1.0f, tau1 = m1 - 1.0f;

  // -------- full-register sweeps until converged or compactable --------
  bool done0 = false, done1 = false;
  bool compactable = false;
  for (int it = 0; it < 24; ++it) {
    float a1 = 0.f, a2 = 0.f, ac = 0.f;
    float b1 = 0.f, b2 = 0.f, bc = 0.f;
#pragma unroll
    for (int j = 0; j < J; ++j) {
      float t0 = x0[j] - tau0, r0 = fmaxf(t0, 0.f);
      a1 += r0; a2 = fmaf(r0, r0, a2); ac += (t0 > 0.f) ? 1.f : 0.f;
      float t1 = x1[j] - tau1, r1 = fmaxf(t1, 0.f);
      b1 += r1; b2 = fmaf(r1, r1, b2); bc += (t1 > 0.f) ? 1.f : 0.f;
    }
#pragma unroll
    for (int off = 32; off >= 1; off >>= 1) {
      a1 += __shfl_xor(a1, off); a2 += __shfl_xor(a2, off);
      ac += __shfl_xor(ac, off);
      b1 += __shfl_xor(b1, off); b2 += __shfl_xor(b2, off);
      bc += __shfl_xor(bc, off);
    }
    float f0 = a2 - 1.0f, f1 = b2 - 1.0f;
    bool g0 = !done0 && (f0 > 1e-6f) && (a1 > 1e-12f);
    bool g1 = !done1 && (f1 > 1e-6f) && (b1 > 1e-12f);
    if (g0) tau0 += hstep(f0, a1, ac); else done0 = true;
    if (g1) tau1 += hstep(f1, b1, bc); else done1 = true;
    if (ac <= (float)CAP && bc <= (float)CAP) { compactable = true; break; }
    if (done0 && done1) break;
  }

  float* arow = Aout + ((size_t)bh * LROW + row0) * LCOL;
  const float* Vb = ValM + (size_t)bh * LCOL * 16;
  float* op = OutWs + ((size_t)bb * LROW + row0) * 128 + h * 16;

  if (compactable) {
    // -------- compact survivors via wave prefix-sum --------
    int c0 = 0, c1 = 0;
#pragma unroll
    for (int j = 0; j < J; ++j) {
      c0 += (x0[j] > tau0) ? 1 : 0;
      c1 += (x1[j] > tau1) ? 1 : 0;
    }
    int i0 = c0, i1 = c1;
#pragma unroll
    for (int off = 1; off <= 32; off <<= 1) {
      int t0 = __shfl_up(i0, off);
      int t1 = __shfl_up(i1, off);
      if (lane >= off) { i0 += t0; i1 += t1; }
    }
    int base0 = i0 - c0, base1 = i1 - c1;
    int tot0 = __shfl(i0, 63), tot1 = __shfl(i1, 63);
    int w0 = 0, w1 = 0;
#pragma unroll
    for (int j = 0; j < J; ++j) {
      if (x0[j] > tau0) {
        sval[ws][0][base0 + w0] = x0[j];
        sidx[ws][0][base0 + w0] = (unsigned short)(lane + 64 * j);
        ++w0;
      }
      if (x1[j] > tau1) {
        sval[ws][1][base1 + w1] = x1[j];
        sidx[ws][1][base1 + w1] = (unsigned short)(lane + 64 * j);
        ++w1;
      }
    }
    __threadfence_block();   // wave-local LDS visibility across lanes

    // -------- compacted solver --------
    if (!(done0 && done1)) {
      for (int it = 0; it < 24; ++it) {
        float a1 = 0.f, a2 = 0.f, ac = 0.f;
        float b1 = 0.f, b2 = 0.f, bc = 0.f;
        for (int i = lane; i < tot0; i += 64) {
          float t = sval[ws][0][i] - tau0, r = fmaxf(t, 0.f);
          a1 += r; a2 = fmaf(r, r, a2); ac += (t > 0.f) ? 1.f : 0.f;
        }
        for (int i = lane; i < tot1; i += 64) {
          float t = sval[ws][1][i] - tau1, r = fmaxf(t, 0.f);
          b1 += r; b2 = fmaf(r, r, b2); bc += (t > 0.f) ? 1.f : 0.f;
        }
#pragma unroll
        for (int off = 32; off >= 1; off >>= 1) {
          a1 += __shfl_xor(a1, off); a2 += __shfl_xor(a2, off);
          ac += __shfl_xor(ac, off);
          b1 += __shfl_xor(b1, off); b2 += __shfl_xor(b2, off);
          bc += __shfl_xor(bc, off);
        }
        float f0 = a2 - 1.0f, f1 = b2 - 1.0f;
        bool g0 = !done0 && (f0 > 1e-6f) && (a1 > 1e-12f);
        bool g1 = !done1 && (f1 > 1e-6f) && (b1 > 1e-12f);
        if (g0) tau0 += hstep(f0, a1, ac); else done0 = true;
        if (g1) tau1 += hstep(f1, b1, bc); else done1 = true;
        if (done0 && done1) break;
      }
    }

    // -------- dense A write from live score registers (coalesced) --------
#pragma unroll
    for (int j = 0; j < J; ++j) {
      int kk = lane + 64 * j;
      float t0 = fmaxf(x0[j] - tau0, 0.f);
      float t1 = fmaxf(x1[j] - tau1, 0.f);
      arow[kk]        = t0 * t0;
      arow[LCOL + kk] = t1 * t1;
    }

    // -------- sparse P@V over survivors --------
    float acc0[16], acc1[16];
#pragma unroll
    for (int d = 0; d < 16; ++d) { acc0[d] = 0.f; acc1[d] = 0.f; }
    for (int i = lane; i < tot0; i += 64) {
      float t = sval[ws][0][i] - tau0;
      if (t > 0.f) {
        float p = t * t;
        int kk = sidx[ws][0][i];
        const float4* vp = (const float4*)(Vb + (size_t)kk * 16);
        float4 v0 = vp[0], v1 = vp[1], v2 = vp[2], v3 = vp[3];
        float vf[16] = { v0.x, v0.y, v0.z, v0.w, v1.x, v1.y, v1.z, v1.w,
                         v2.x, v2.y, v2.z, v2.w, v3.x, v3.y, v3.z, v3.w };
#pragma unroll
        for (int d = 0; d < 16; ++d) acc0[d] = fmaf(p, vf[d], acc0[d]);
      }
    }
    for (int i = lane; i < tot1; i += 64) {
      float t = sval[ws][1][i] - tau1;
      if (t > 0.f) {
        float p = t * t;
        int kk = sidx[ws][1][i];
        const float4* vp = (const float4*)(Vb + (size_t)kk * 16);
        float4 v0 = vp[0], v1 = vp[1], v2 = vp[2], v3 = vp[3];
        float vf[16] = { v0.x, v0.y, v0.z, v0.w, v1.x, v1.y, v1.z, v1.w,
                         v2.x, v2.y, v2.z, v2.w, v3.x, v3.y, v3.z, v3.w };
#pragma unroll
        for (int d = 0; d < 16; ++d) acc1[d] = fmaf(p, vf[d], acc1[d]);
      }
    }
#pragma unroll
    for (int off = 32; off >= 1; off >>= 1)
#pragma unroll
      for (int d = 0; d < 16; ++d) {
        acc0[d] += __shfl_xor(acc0[d], off);
        acc1[d] += __shfl_xor(acc1[d], off);
      }
    float v0l = acc0[0], v1l = acc1[0];
#pragma unroll
    for (int d = 1; d < 16; ++d) {
      v0l = (lane == d) ? acc0[d] : v0l;
      v1l = (lane == d) ? acc1[d] : v1l;
    }
    if (lane < 16) { op[lane] = v0l; op[128 + lane] = v1l; }
    return;
  }

  // -------- fallback: dense A write + P@V (rare; large-support rows) --------
  float acc0[16], acc1[16];
#pragma unroll
  for (int d = 0; d < 16; ++d) { acc0[d] = 0.f; acc1[d] = 0.f; }
#pragma unroll
  for (int j = 0; j < J; ++j) {
    int kk = lane + 64 * j;
    float t0 = fmaxf(x0[j] - tau0, 0.f), p0 = t0 * t0;
    float t1 = fmaxf(x1[j] - tau1, 0.f), p1 = t1 * t1;
    arow[kk]        = p0;
    arow[LCOL + kk] = p1;
    const float4* vp = (const float4*)(Vb + (size_t)kk * 16);
    float4 v0 = vp[0], v1 = vp[1], v2 = vp[2], v3 = vp[3];
    float vf[16] = { v0.x, v0.y, v0.z, v0.w, v1.x, v1.y, v1.z, v1.w,
                     v2.x, v2.y, v2.z, v2.w, v3.x, v3.y, v3.z, v3.w };
#pragma unroll
    for (int d = 0; d < 16; ++d) {
      acc0[d] = fmaf(p0, vf[d], acc0[d]);
      acc1[d] = fmaf(p1, vf[d], acc1[d]);
    }
  }
#pragma unroll
  for (int off = 32; off >= 1; off >>= 1)
#pragma unroll
    for (int d = 0; d < 16; ++d) {
      acc0[d] += __shfl_xor(acc0[d], off);
      acc1[d] += __shfl_xor(acc1[d], off);
    }
  float w0 = acc0[0], w1 = acc1[0];
#pragma unroll
  for (int d = 1; d < 16; ++d) {
    w0 = (lane == d) ? acc0[d] : w0;
    w1 = (lane == d) ? acc1[d] : w1;
  }
  if (lane < 16) { op[lane] = w0; op[128 + lane] = w1; }
}

// ---------------------------------------------------------------------------
// Y = X1 @ W1 + bias + X2 @ W2 (fp32). 4 rows per block, LDS-staged X.
// ---------------------------------------------------------------------------
__global__ __launch_bounds__(128) void combine_kernel(
    const float* __restrict__ X1, const float* __restrict__ X2,
    const float* __restrict__ W1, const float* __restrict__ W2,
    const float* __restrict__ bias, float* __restrict__ Yo)
{
  __shared__ float x1s[4][128], x2s[4][128];
  int rb = blockIdx.x * 4;
  int c  = threadIdx.x;
#pragma unroll
  for (int i = 0; i < 4; ++i) {
    x1s[i][c] = X1[(size_t)(rb + i) * 128 + c];
    x2s[i][c] = X2[(size_t)(rb + i) * 128 + c];
  }
  __syncthreads();
  float b = bias[c];
  float a0 = b, a1 = b, a2 = b, a3 = b;
#pragma unroll 4
  for (int d = 0; d < 128; ++d) {
    float w1 = W1[d * 128 + c];
    float w2 = W2[d * 128 + c];
    a0 = fmaf(x1s[0][d], w1, fmaf(x2s[0][d], w2, a0));
    a1 = fmaf(x1s[1][d], w1, fmaf(x2s[1][d], w2, a1));
    a2 = fmaf(x1s[2][d], w1, fmaf(x2s[2][d], w2, a2));
    a3 = fmaf(x1s[3][d], w1, fmaf(x2s[3][d], w2, a3));
  }
  Yo[(size_t)(rb + 0) * 128 + c] = a0;
  Yo[(size_t)(rb + 1) * 128 + c] = a1;
  Yo[(size_t)(rb + 2) * 128 + c] = a2;
  Yo[(size_t)(rb + 3) * 128 + c] = a3;
}

// ---------------------------------------------------------------------------
// LayerNorm + ReLU. 4 rows per block (one wave each).
// ---------------------------------------------------------------------------
__global__ __launch_bounds__(256) void ln_kernel(
    const float* __restrict__ Y1, const float* __restrict__ Y2,
    const float* __restrict__ gamma, const float* __restrict__ beta,
    float* __restrict__ O1, float* __restrict__ O2, int R1)
{
  int row  = blockIdx.x * 4 + (threadIdx.x >> 6);
  int lane = threadIdx.x & 63;
  const float* y = (row < R1) ? (Y1 + (size_t)row * 128)
                              : (Y2 + (size_t)(row - R1) * 128);
  float* o = (row < R1) ? (O1 + (size_t)row * 128)
                        : (O2 + (size_t)(row - R1) * 128);
  float a0 = y[lane];
  float a1 = y[lane + 64];
  float s  = a0 + a1;
  float s2 = fmaf(a0, a0, a1 * a1);
#pragma unroll
  for (int off = 32; off >= 1; off >>= 1) {
    s  += __shfl_xor(s, off);
    s2 += __shfl_xor(s2, off);
  }
  float mu  = s * (1.f / 128.f);
  float var = fmaxf(s2 * (1.f / 128.f) - mu * mu, 0.f);
  float rs  = rsqrtf(var + 1e-5f);
  float o0 = fmaxf(fmaf((a0 - mu) * rs, gamma[lane],      beta[lane]),      0.f);
  float o1 = fmaxf(fmaf((a1 - mu) * rs, gamma[lane + 64], beta[lane + 64]), 0.f);
  o[lane]      = o0;
  o[lane + 64] = o1;
}

// ---------------------------------------------------------------------------
extern "C"
__attribute__((visibility("default"), used))
void kernel_launch(void* const* d_in, const int* in_sizes, int n_in,
                   void* d_out, int out_size, void* d_ws, size_t ws_size,
                   hipStream_t stream)
{
  (void)in_sizes; (void)n_in; (void)out_size; (void)ws_size;
  const float* q     = (const float*)d_in[0];
  const float* k     = (const float*)d_in[1];
  const float* v     = (const float*)d_in[2];
  const float* v2    = (const float*)d_in[3];
  const float* W_Q   = (const float*)d_in[4];
  const float* b_Q   = (const float*)d_in[5];
  const float* W_K   = (const float*)d_in[6];
  const float* b_K   = (const float*)d_in[7];
  const float* W_V   = (const float*)d_in[8];
  const float* b_V   = (const float*)d_in[9];
  const float* W_V2  = (const float*)d_in[10];
  const float* b_V2  = (const float*)d_in[11];
  const float* W_O   = (const float*)d_in[12];
  const float* b_O   = (const float*)d_in[13];
  const float* W_O2  = (const float*)d_in[14];
  const float* b_O2  = (const float*)d_in[15];
  const float* W_R   = (const float*)d_in[16];
  const float* W_R2  = (const float*)d_in[17];
  const float* gamma = (const float*)d_in[18];
  const float* beta  = (const float*)d_in[19];

  char* ws = (char*)d_ws;
  const size_t MB = 1u << 20;
  float* Qp    = (float*)(ws + 0);        // chunk-major [bh][4][1024][4]
  float* Kp    = (float*)(ws + 2 * MB);   // chunk-major [bh][4][2048][4]
  float* Vp    = (float*)(ws + 6 * MB);   // row-major   [bh][2048][16]
  float* V2p   = (float*)(ws + 10 * MB);  // row-major   [bh][1024][16]
  float* outm1 = (float*)(ws + 12 * MB);
  float* outm2 = (float*)(ws + 14 * MB);
  float* outy1 = (float*)(ws + 18 * MB);
  float* outy2 = (float*)(ws + 20 * MB);

  float* out1  = (float*)d_out;              // (4,1024,128)
  float* out2  = out1 + (size_t)524288;      // (4,2048,128)
  float* Aout  = out1 + (size_t)1572864;     // (4,8,1024,2048)
  float* A2out = out1 + (size_t)68681728;    // (4,8,2048,1024)

  proj_kernel<1><<<1024, 128, 0, stream>>>(q,  W_Q,  b_Q,  Qp,  1024);
  proj_kernel<1><<<2048, 128, 0, stream>>>(k,  W_K,  b_K,  Kp,  2048);
  proj_kernel<0><<<2048, 128, 0, stream>>>(v,  W_V,  b_V,  Vp,  2048);
  proj_kernel<0><<<1024, 128, 0, stream>>>(v2, W_V2, b_V2, V2p, 1024);

  attn_kernel<1024, 2048><<<4096, 256, 0, stream>>>(Qp, Kp, Vp,  Aout,  outm1);
  attn_kernel<2048, 1024><<<8192, 256, 0, stream>>>(Kp, Qp, V2p, A2out, outm2);

  combine_kernel<<<1024, 128, 0, stream>>>(outm1, q, W_O,  W_R,  b_O,  outy1);
  combine_kernel<<<2048, 128, 0, stream>>>(outm2, k, W_O2, W_R2, b_O2, outy2);

  ln_kernel<<<3072, 256, 0, stream>>>(outy1, outy2, gamma, beta,
                                      out1, out2, 4096);
}

// Round 2
// 1191.048 us; speedup vs baseline: 1.2688x; 1.2688x over previous
//
#include <hip/hip_runtime.h>

// ---------------------------------------------------------------------------
// All four projections in one launch. 4 rows per block, 128 threads.
// CHUNKED=0: Y[((bb*8+h)*L + l)*16 + dd]                      (row layout, V)
// CHUNKED=1: Y[(((bb*8+h)*4 + dd/4)*L + l)*4 + dd%4]   (chunk-major, Q and K)
// ---------------------------------------------------------------------------
__global__ __launch_bounds__(128) void proj_all_kernel(
    const float* __restrict__ q, const float* __restrict__ k,
    const float* __restrict__ v, const float* __restrict__ v2,
    const float* __restrict__ W_Q, const float* __restrict__ b_Q,
    const float* __restrict__ W_K, const float* __restrict__ b_K,
    const float* __restrict__ W_V, const float* __restrict__ b_V,
    const float* __restrict__ W_V2, const float* __restrict__ b_V2,
    float* __restrict__ Qp, float* __restrict__ Kp,
    float* __restrict__ Vp, float* __restrict__ V2p)
{
  __shared__ float xs[4][128];
  int blk = blockIdx.x;
  const float *X, *W, *B; float* Y; int L, chunked, rb;
  if (blk < 1024)      { X = q;  W = W_Q;  B = b_Q;  Y = Qp;  L = 1024; chunked = 1; rb = blk; }
  else if (blk < 3072) { X = k;  W = W_K;  B = b_K;  Y = Kp;  L = 2048; chunked = 1; rb = blk - 1024; }
  else if (blk < 5120) { X = v;  W = W_V;  B = b_V;  Y = Vp;  L = 2048; chunked = 0; rb = blk - 3072; }
  else                 { X = v2; W = W_V2; B = b_V2; Y = V2p; L = 1024; chunked = 0; rb = blk - 5120; }
  rb *= 4;
  int c = threadIdx.x;
#pragma unroll
  for (int i = 0; i < 4; ++i)
    xs[i][c] = X[(size_t)(rb + i) * 128 + c];
  __syncthreads();
  float b = B[c];
  float a0 = b, a1 = b, a2 = b, a3 = b;
#pragma unroll 8
  for (int d = 0; d < 128; ++d) {
    float w = W[d * 128 + c];
    a0 = fmaf(xs[0][d], w, a0);
    a1 = fmaf(xs[1][d], w, a1);
    a2 = fmaf(xs[2][d], w, a2);
    a3 = fmaf(xs[3][d], w, a3);
  }
  int h = c >> 4, dd = c & 15;
  float av[4] = { a0, a1, a2, a3 };
#pragma unroll
  for (int i = 0; i < 4; ++i) {
    int row = rb + i;
    int bb = row / L;
    int l  = row - bb * L;
    if (chunked)
      Y[(((size_t)(bb * 8 + h) * 4 + (dd >> 2)) * L + l) * 4 + (dd & 3)] = av[i];
    else
      Y[((size_t)(bb * 8 + h) * L + l) * 16 + dd] = av[i];
  }
}

// Guarded hybrid root step for f(u-shifted) = S2 - 1 over current support:
// exact segment root when discriminant real, else Newton.
static __device__ __forceinline__ float hstep(float f, float s1, float cnt)
{
  float arg = fmaf(-cnt, f, s1 * s1);
  return (arg > 0.f) ? f / (s1 + sqrtf(arg)) : f / (2.f * s1);
}

// ---------------------------------------------------------------------------
// Attention pass (fp32). One wave per 2 rows. Scores in registers
// (k = lane + 64*j). RowM/ColM chunk-major so score loads are 16B/lane
// contiguous. Support counts via __ballot -> SGPR (no count butterflies).
// Dense solver: 4-value 6-level butterfly. Once support <= CAP, survivors
// compacted to per-wave LDS; the compacted solver and sparse P@V are
// HALF-WAVE SPLIT (lanes 0-31 own row0, 32-63 own row1): halves loop trips,
// halves the final reduction, and halves accumulator registers.
// ---------------------------------------------------------------------------
template<int LROW, int LCOL>
__global__ __launch_bounds__(256, 4) void attn_kernel(
    const float* __restrict__ RowM, const float* __restrict__ ColM,
    const float* __restrict__ ValM, float* __restrict__ Aout,
    float* __restrict__ OutWs)
{
  constexpr int J   = LCOL / 64;
  constexpr int CAP = 512;
  __shared__ float          sval[4][2][CAP];
  __shared__ unsigned short sidx[4][2][CAP];

  int ws   = threadIdx.x >> 6;                      // wave slot in block
  int pid  = blockIdx.x * 4 + ws;                   // row-pair id
  int lane = threadIdx.x & 63;
  int half   = lane >> 5;                           // 0 -> row0 duty, 1 -> row1
  int lane31 = lane & 31;
  int bh   = pid / (LROW / 2);
  int pr   = pid - bh * (LROW / 2);
  int row0 = pr * 2;
  int bb   = bh >> 3, h = bh & 7;

  float qf0[16], qf1[16];
  { const float* qb = RowM + (size_t)bh * LROW * 16;   // chunk-major block
#pragma unroll
    for (int d = 0; d < 16; ++d) {
      qf0[d] = qb[((size_t)(d >> 2) * LROW + row0)     * 4 + (d & 3)] * 0.125f;
      qf1[d] = qb[((size_t)(d >> 2) * LROW + row0 + 1) * 4 + (d & 3)] * 0.125f;
    } }

  // -------- scores (raw; max folded into tau0) --------
  float x0[J], x1[J];
  const float4* Cb = (const float4*)(ColM + (size_t)bh * LCOL * 16);
#pragma unroll
  for (int j = 0; j < J; ++j) {
    int kk = lane + 64 * j;
    float4 k0 = Cb[0 * LCOL + kk];      // 16B/lane contiguous -> 1KB/wave
    float4 k1 = Cb[1 * LCOL + kk];
    float4 k2 = Cb[2 * LCOL + kk];
    float4 k3 = Cb[3 * LCOL + kk];
    float kf[16] = { k0.x, k0.y, k0.z, k0.w, k1.x, k1.y, k1.z, k1.w,
                     k2.x, k2.y, k2.z, k2.w, k3.x, k3.y, k3.z, k3.w };
    float s0 = 0.f, s1 = 0.f;
#pragma unroll
    for (int d = 0; d < 16; ++d) {
      s0 = fmaf(qf0[d], kf[d], s0);
      s1 = fmaf(qf1[d], kf[d], s1);
    }
    x0[j] = s0; x1[j] = s1;
  }

  float m0 = -1e30f, m1 = -1e30f;
#pragma unroll
  for (int j = 0; j < J; ++j) { m0 = fmaxf(m0, x0[j]); m1 = fmaxf(m1, x1[j]); }
#pragma unroll
  for (int off = 32; off >= 1; off >>= 1) {
    m0 = fmaxf(m0, __shfl_xor(m0, off));
    m1 = fmaxf(m1, __shfl_xor(m1, off));
  }

  float tau0 = m0 - 1.0f, tau1 = m1 - 1.0f;

  // -------- full-register sweeps until converged or compactable --------
  bool done0 = false, done1 = false;
  bool compactable = false;
  for (int it = 0; it < 24; ++it) {
    float a1 = 0.f, a2 = 0.f;
    float b1 = 0.f, b2 = 0.f;
    int ac = 0, bc = 0;                       // wave-uniform (ballot/popc)
#pragma unroll
    for (int j = 0; j < J; ++j) {
      float t0 = x0[j] - tau0, r0 = fmaxf(t0, 0.f);
      a1 += r0; a2 = fmaf(r0, r0, a2);
      ac += __popcll(__ballot(t0 > 0.f));
      float t1 = x1[j] - tau1, r1 = fmaxf(t1, 0.f);
      b1 += r1; b2 = fmaf(r1, r1, b2);
      bc += __popcll(__ballot(t1 > 0.f));
    }
#pragma unroll
    for (int off = 32; off >= 1; off >>= 1) {
      a1 += __shfl_xor(a1, off); a2 += __shfl_xor(a2, off);
      b1 += __shfl_xor(b1, off); b2 += __shfl_xor(b2, off);
    }
    float f0 = a2 - 1.0f, f1 = b2 - 1.0f;
    bool g0 = !done0 && (f0 > 1e-6f) && (a1 > 1e-12f);
    bool g1 = !done1 && (f1 > 1e-6f) && (b1 > 1e-12f);
    if (g0) tau0 += hstep(f0, a1, (float)ac); else done0 = true;
    if (g1) tau1 += hstep(f1, b1, (float)bc); else done1 = true;
    if (ac <= CAP && bc <= CAP) { compactable = true; break; }
    if (done0 && done1) break;
  }

  float* arow = Aout + ((size_t)bh * LROW + row0) * LCOL;
  const float* Vb = ValM + (size_t)bh * LCOL * 16;
  float* op = OutWs + ((size_t)bb * LROW + row0) * 128 + h * 16;

  if (compactable) {
    // -------- compact survivors via wave prefix-sum --------
    int c0 = 0, c1 = 0;
#pragma unroll
    for (int j = 0; j < J; ++j) {
      c0 += (x0[j] > tau0) ? 1 : 0;
      c1 += (x1[j] > tau1) ? 1 : 0;
    }
    int i0 = c0, i1 = c1;
#pragma unroll
    for (int off = 1; off <= 32; off <<= 1) {
      int t0 = __shfl_up(i0, off);
      int t1 = __shfl_up(i1, off);
      if (lane >= off) { i0 += t0; i1 += t1; }
    }
    int base0 = i0 - c0, base1 = i1 - c1;
    int tot0 = __shfl(i0, 63), tot1 = __shfl(i1, 63);
    int w0 = 0, w1 = 0;
#pragma unroll
    for (int j = 0; j < J; ++j) {
      if (x0[j] > tau0) {
        sval[ws][0][base0 + w0] = x0[j];
        sidx[ws][0][base0 + w0] = (unsigned short)(lane + 64 * j);
        ++w0;
      }
      if (x1[j] > tau1) {
        sval[ws][1][base1 + w1] = x1[j];
        sidx[ws][1][base1 + w1] = (unsigned short)(lane + 64 * j);
        ++w1;
      }
    }
    __threadfence_block();   // wave-local LDS visibility across lanes

    // -------- compacted solver, half-wave split (half h owns row h) ------
    const float*          svp = &sval[ws][half][0];
    const unsigned short* sip = &sidx[ws][half][0];
    int   tot_my  = half ? tot1 : tot0;
    float tau_my  = half ? tau1 : tau0;
    bool  done_my = half ? done1 : done0;
    if (!(done0 && done1)) {
      for (int it = 0; it < 24; ++it) {
        float s1 = 0.f, s2 = 0.f, cm = 0.f;
        for (int i = lane31; i < tot_my; i += 32) {
          float t = svp[i] - tau_my, r = fmaxf(t, 0.f);
          s1 += r; s2 = fmaf(r, r, s2); cm += (t > 0.f) ? 1.f : 0.f;
        }
#pragma unroll
        for (int off = 16; off >= 1; off >>= 1) {   // stays within half
          s1 += __shfl_xor(s1, off);
          s2 += __shfl_xor(s2, off);
          cm += __shfl_xor(cm, off);
        }
        float f = s2 - 1.0f;
        bool g = !done_my && (f > 1e-6f) && (s1 > 1e-12f);
        if (g) tau_my += hstep(f, s1, cm); else done_my = true;
        if (__ballot(done_my) == ~0ull) break;
      }
    }
    tau0 = __shfl(tau_my, 0);
    tau1 = __shfl(tau_my, 32);

    // -------- dense A write from live score registers (coalesced) --------
#pragma unroll
    for (int j = 0; j < J; ++j) {
      int kk = lane + 64 * j;
      float t0 = fmaxf(x0[j] - tau0, 0.f);
      float t1 = fmaxf(x1[j] - tau1, 0.f);
      arow[kk]        = t0 * t0;
      arow[LCOL + kk] = t1 * t1;
    }

    // -------- sparse P@V, half-wave split --------
    float acc[16];
#pragma unroll
    for (int d = 0; d < 16; ++d) acc[d] = 0.f;
    for (int i = lane31; i < tot_my; i += 32) {
      float t = svp[i] - tau_my;
      if (t > 0.f) {
        float p = t * t;
        int kk = sip[i];
        const float4* vp = (const float4*)(Vb + (size_t)kk * 16);
        float4 v0 = vp[0], v1 = vp[1], v2 = vp[2], v3 = vp[3];
        float vf[16] = { v0.x, v0.y, v0.z, v0.w, v1.x, v1.y, v1.z, v1.w,
                         v2.x, v2.y, v2.z, v2.w, v3.x, v3.y, v3.z, v3.w };
#pragma unroll
        for (int d = 0; d < 16; ++d) acc[d] = fmaf(p, vf[d], acc[d]);
      }
    }
#pragma unroll
    for (int off = 16; off >= 1; off >>= 1)         // stays within half
#pragma unroll
      for (int d = 0; d < 16; ++d) acc[d] += __shfl_xor(acc[d], off);
    float vv = acc[0];
#pragma unroll
    for (int d = 1; d < 16; ++d)
      vv = ((lane & 15) == d) ? acc[d] : vv;
    if (lane31 < 16) op[half * 128 + lane31] = vv;
    return;
  }

  // -------- fallback: dense A write + P@V, two passes sharing acc[16] ----
#pragma unroll
  for (int pass = 0; pass < 2; ++pass) {
    float taup = pass ? tau1 : tau0;
    float acc[16];
#pragma unroll
    for (int d = 0; d < 16; ++d) acc[d] = 0.f;
#pragma unroll
    for (int j = 0; j < J; ++j) {
      int kk = lane + 64 * j;
      float xv = pass ? x1[j] : x0[j];
      float t = fmaxf(xv - taup, 0.f), p = t * t;
      arow[(size_t)pass * LCOL + kk] = p;
      const float4* vp = (const float4*)(Vb + (size_t)kk * 16);
      float4 v0 = vp[0], v1 = vp[1], v2 = vp[2], v3 = vp[3];
      float vf[16] = { v0.x, v0.y, v0.z, v0.w, v1.x, v1.y, v1.z, v1.w,
                       v2.x, v2.y, v2.z, v2.w, v3.x, v3.y, v3.z, v3.w };
#pragma unroll
      for (int d = 0; d < 16; ++d) acc[d] = fmaf(p, vf[d], acc[d]);
    }
#pragma unroll
    for (int off = 32; off >= 1; off >>= 1)
#pragma unroll
      for (int d = 0; d < 16; ++d) acc[d] += __shfl_xor(acc[d], off);
    float vv = acc[0];
#pragma unroll
    for (int d = 1; d < 16; ++d)
      vv = (lane == d) ? acc[d] : vv;
    if (lane < 16) op[pass * 128 + lane] = vv;
  }
}

// ---------------------------------------------------------------------------
// Fused: Y = X1 @ W1 + bias + X2 @ W2, then LayerNorm(gamma,beta) + ReLU.
// 4 rows per block, 128 threads (one output column each, 2 waves).
// Row stats via wave butterfly + tiny LDS cross-wave combine.
// ---------------------------------------------------------------------------
__global__ __launch_bounds__(128) void combine_ln_kernel(
    const float* __restrict__ X1, const float* __restrict__ X2,
    const float* __restrict__ W1, const float* __restrict__ W2,
    const float* __restrict__ bias, const float* __restrict__ gamma,
    const float* __restrict__ beta, float* __restrict__ O)
{
  __shared__ float x1s[4][128], x2s[4][128];
  __shared__ float red[2][8];
  int rb = blockIdx.x * 4;
  int c  = threadIdx.x;
#pragma unroll
  for (int i = 0; i < 4; ++i) {
    x1s[i][c] = X1[(size_t)(rb + i) * 128 + c];
    x2s[i][c] = X2[(size_t)(rb + i) * 128 + c];
  }
  __syncthreads();
  float b = bias[c];
  float a0 = b, a1 = b, a2 = b, a3 = b;
#pragma unroll 4
  for (int d = 0; d < 128; ++d) {
    float w1 = W1[d * 128 + c];
    float w2 = W2[d * 128 + c];
    a0 = fmaf(x1s[0][d], w1, fmaf(x2s[0][d], w2, a0));
    a1 = fmaf(x1s[1][d], w1, fmaf(x2s[1][d], w2, a1));
    a2 = fmaf(x1s[2][d], w1, fmaf(x2s[2][d], w2, a2));
    a3 = fmaf(x1s[3][d], w1, fmaf(x2s[3][d], w2, a3));
  }
  // per-row sums and sum-squares over the 128 columns
  float s0 = a0, s1 = a1, s2 = a2, s3 = a3;
  float q0 = a0 * a0, q1 = a1 * a1, q2 = a2 * a2, q3 = a3 * a3;
#pragma unroll
  for (int off = 32; off >= 1; off >>= 1) {
    s0 += __shfl_xor(s0, off); q0 += __shfl_xor(q0, off);
    s1 += __shfl_xor(s1, off); q1 += __shfl_xor(q1, off);
    s2 += __shfl_xor(s2, off); q2 += __shfl_xor(q2, off);
    s3 += __shfl_xor(s3, off); q3 += __shfl_xor(q3, off);
  }
  int wv = c >> 6;
  if ((c & 63) == 0) {
    red[wv][0] = s0; red[wv][1] = q0; red[wv][2] = s1; red[wv][3] = q1;
    red[wv][4] = s2; red[wv][5] = q2; red[wv][6] = s3; red[wv][7] = q3;
  }
  __syncthreads();
  float S0 = red[0][0] + red[1][0], Q0 = red[0][1] + red[1][1];
  float S1 = red[0][2] + red[1][2], Q1 = red[0][3] + red[1][3];
  float S2 = red[0][4] + red[1][4], Q2 = red[0][5] + red[1][5];
  float S3 = red[0][6] + red[1][6], Q3 = red[0][7] + red[1][7];
  float g = gamma[c], be = beta[c];
  float mu, var, rs;
  mu = S0 * (1.f / 128.f); var = fmaxf(Q0 * (1.f / 128.f) - mu * mu, 0.f);
  rs = rsqrtf(var + 1e-5f);
  O[(size_t)(rb + 0) * 128 + c] = fmaxf(fmaf((a0 - mu) * rs, g, be), 0.f);
  mu = S1 * (1.f / 128.f); var = fmaxf(Q1 * (1.f / 128.f) - mu * mu, 0.f);
  rs = rsqrtf(var + 1e-5f);
  O[(size_t)(rb + 1) * 128 + c] = fmaxf(fmaf((a1 - mu) * rs, g, be), 0.f);
  mu = S2 * (1.f / 128.f); var = fmaxf(Q2 * (1.f / 128.f) - mu * mu, 0.f);
  rs = rsqrtf(var + 1e-5f);
  O[(size_t)(rb + 2) * 128 + c] = fmaxf(fmaf((a2 - mu) * rs, g, be), 0.f);
  mu = S3 * (1.f / 128.f); var = fmaxf(Q3 * (1.f / 128.f) - mu * mu, 0.f);
  rs = rsqrtf(var + 1e-5f);
  O[(size_t)(rb + 3) * 128 + c] = fmaxf(fmaf((a3 - mu) * rs, g, be), 0.f);
}

// ---------------------------------------------------------------------------
extern "C"
__attribute__((visibility("default"), used))
void kernel_launch(void* const* d_in, const int* in_sizes, int n_in,
                   void* d_out, int out_size, void* d_ws, size_t ws_size,
                   hipStream_t stream)
{
  (void)in_sizes; (void)n_in; (void)out_size; (void)ws_size;
  const float* q     = (const float*)d_in[0];
  const float* k     = (const float*)d_in[1];
  const float* v     = (const float*)d_in[2];
  const float* v2    = (const float*)d_in[3];
  const float* W_Q   = (const float*)d_in[4];
  const float* b_Q   = (const float*)d_in[5];
  const float* W_K   = (const float*)d_in[6];
  const float* b_K   = (const float*)d_in[7];
  const float* W_V   = (const float*)d_in[8];
  const float* b_V   = (const float*)d_in[9];
  const float* W_V2  = (const float*)d_in[10];
  const float* b_V2  = (const float*)d_in[11];
  const float* W_O   = (const float*)d_in[12];
  const float* b_O   = (const float*)d_in[13];
  const float* W_O2  = (const float*)d_in[14];
  const float* b_O2  = (const float*)d_in[15];
  const float* W_R   = (const float*)d_in[16];
  const float* W_R2  = (const float*)d_in[17];
  const float* gamma = (const float*)d_in[18];
  const float* beta  = (const float*)d_in[19];

  char* ws = (char*)d_ws;
  const size_t MB = 1u << 20;
  float* Qp    = (float*)(ws + 0);        // chunk-major [bh][4][1024][4]
  float* Kp    = (float*)(ws + 2 * MB);   // chunk-major [bh][4][2048][4]
  float* Vp    = (float*)(ws + 6 * MB);   // row-major   [bh][2048][16]
  float* V2p   = (float*)(ws + 10 * MB);  // row-major   [bh][1024][16]
  float* outm1 = (float*)(ws + 12 * MB);
  float* outm2 = (float*)(ws + 14 * MB);

  float* out1  = (float*)d_out;              // (4,1024,128)
  float* out2  = out1 + (size_t)524288;      // (4,2048,128)
  float* Aout  = out1 + (size_t)1572864;     // (4,8,1024,2048)
  float* A2out = out1 + (size_t)68681728;    // (4,8,2048,1024)

  proj_all_kernel<<<6144, 128, 0, stream>>>(
      q, k, v, v2, W_Q, b_Q, W_K, b_K, W_V, b_V, W_V2, b_V2,
      Qp, Kp, Vp, V2p);

  attn_kernel<1024, 2048><<<4096, 256, 0, stream>>>(Qp, Kp, Vp,  Aout,  outm1);
  attn_kernel<2048, 1024><<<8192, 256, 0, stream>>>(Kp, Qp, V2p, A2out, outm2);

  combine_ln_kernel<<<1024, 128, 0, stream>>>(outm1, q, W_O,  W_R,  b_O,
                                              gamma, beta, out1);
  combine_ln_kernel<<<2048, 128, 0, stream>>>(outm2, k, W_O2, W_R2, b_O2,
                                              gamma, beta, out2);
}